// Round 3
// baseline (2070.084 us; speedup 1.0000x reference)
//
#include <hip/hip_runtime.h>
#include <hip/hip_bf16.h>

typedef __hip_bfloat16 bf16;

__device__ __forceinline__ float bf2f(bf16 v) { return __bfloat162float(v); }

// dtype-dispatching loads (flag-driven, uniform branch)
__device__ __forceinline__ float ldf(const void* p, size_t i, bool isbf) {
    return isbf ? bf2f(((const bf16*)p)[i]) : ((const float*)p)[i];
}
__device__ __forceinline__ int ldi(const void* p, size_t i, bool is64) {
    return is64 ? (int)((const long long*)p)[i] : ((const int*)p)[i];
}
__device__ __forceinline__ float sane(float v) {  // sanitize edge weights
    return (v == v && fabsf(v) < 1e30f) ? v : 0.f;
}

// ---------------- dtype detection ----------------
// flags[0]: 1 if floats are bf16, 0 if fp32.  flags[1]: 1 if indices are int64.
__global__ void detect(const unsigned* __restrict__ w1w, const unsigned* __restrict__ eiw,
                       int* __restrict__ flags) {
    __shared__ int cnt[2];
    if (threadIdx.x < 2) cnt[threadIdx.x] = 0;
    __syncthreads();
    int c0 = 0;
    for (int i = threadIdx.x; i < 4096; i += 256) {
        unsigned u = w1w[i];
        unsigned e0 = (u >> 7) & 0xFFu, e1 = (u >> 23) & 0xFFu;
        if (e0 <= 125u && e1 <= 125u) c0++;   // both halves plausible small bf16
    }
    int c1 = 0;
    for (int i = threadIdx.x; i < 2048; i += 256)
        if (eiw[2 * i + 1] == 0u) c1++;       // int64 high words are all zero
    atomicAdd(&cnt[0], c0);
    atomicAdd(&cnt[1], c1);
    __syncthreads();
    if (threadIdx.x == 0) {
        flags[0] = (cnt[0] >= 3072) ? 1 : 0;
        flags[1] = (cnt[1] >= 1024) ? 1 : 0;
    }
}

// ---------------- degree / norm ----------------
__global__ void init_deg(float* __restrict__ deg, int n) {
    int i = blockIdx.x * blockDim.x + threadIdx.x;
    if (i < n) deg[i] = 1.0f;  // self-loop weight
}

__global__ void deg_accum(const void* __restrict__ ei, const void* __restrict__ w,
                          float* __restrict__ deg, const int* __restrict__ flags,
                          int e, int n) {
    const bool isbf = flags[0] != 0;
    const bool is64 = flags[1] != 0;
    int i = blockIdx.x * blockDim.x + threadIdx.x;
    if (i < e) {
        int c = ldi(ei, (size_t)e + i, is64);  // col = edge_index[1][i]
        if ((unsigned)c < (unsigned)n)
            unsafeAtomicAdd(&deg[c], sane(ldf(w, i, isbf)));
    }
}

__global__ void deg_to_dinv(float* __restrict__ deg, int n) {
    int i = blockIdx.x * blockDim.x + threadIdx.x;
    if (i < n) {
        float d = deg[i];
        deg[i] = d > 0.f ? rsqrtf(d) : 0.f;
    }
}

// ---- layer1 GEMM: t1 = dinv ⊙ (X @ W1); G=bf16(t1), S=t1 (self-loop init) ----
__global__ __launch_bounds__(256) void gemm1(const void* __restrict__ x,
                                             const void* __restrict__ W1,
                                             const float* __restrict__ dinv,
                                             const int* __restrict__ flags,
                                             bf16* __restrict__ G,
                                             float* __restrict__ S, int n) {
    const bool isbf = flags[0] != 0;
    __shared__ float ws[128 * 64];  // 32 KB
    for (int i = threadIdx.x; i < 128 * 64; i += 256) ws[i] = ldf(W1, i, isbf);
    __syncthreads();

    const int lane = threadIdx.x & 63;
    const int wid  = (blockIdx.x * 256 + threadIdx.x) >> 6;
    const int nw   = (gridDim.x * 256) >> 6;

    for (int row = wid; row < n; row += nw) {
        const size_t base = (size_t)row * 128;
        const float xa = ldf(x, base + 2 * lane, isbf);
        const float xb = ldf(x, base + 2 * lane + 1, isbf);
        float h = 0.f;
#pragma unroll
        for (int m = 0; m < 64; ++m) {
            h = fmaf(__shfl(xa, m), ws[(2 * m) * 64 + lane], h);
            h = fmaf(__shfl(xb, m), ws[(2 * m + 1) * 64 + lane], h);
        }
        float gv = dinv[row] * h;
        G[(size_t)row * 64 + lane] = __float2bfloat16(gv);
        S[(size_t)row * 64 + lane] = gv;  // self-loop term
    }
}

// ---- scatter (64-dim): S[c] += w_e * G[r]; 2 edges per wave ----
__global__ __launch_bounds__(256) void scatter64(const void* __restrict__ ei,
                                                 const void* __restrict__ w,
                                                 const bf16* __restrict__ G,
                                                 float* __restrict__ S,
                                                 const int* __restrict__ flags,
                                                 int e, int n) {
    const bool isbf = flags[0] != 0;
    const bool is64 = flags[1] != 0;
    const int half = (threadIdx.x >> 5) & 1;  // which edge of the pair
    const int j    = threadIdx.x & 31;        // dim-pair index (dims 2j, 2j+1)
    const int wid  = (blockIdx.x * 256 + threadIdx.x) >> 6;
    const int nw   = (gridDim.x * 256) >> 6;

    for (long i0 = (long)wid * 2; i0 < e; i0 += (long)nw * 2) {
        long i = i0 + half;
        if (i >= e) continue;
        int r = ldi(ei, (size_t)i, is64);
        int c = ldi(ei, (size_t)e + i, is64);
        if ((unsigned)r >= (unsigned)n || (unsigned)c >= (unsigned)n) continue;
        float we = sane(ldf(w, i, isbf));
        unsigned gp = ((const unsigned*)(G + (size_t)r * 64))[j];
        float v0 = we * __uint_as_float((gp & 0xffffu) << 16);
        float v1 = we * __uint_as_float(gp & 0xffff0000u);
        float* a = S + (size_t)c * 64 + 2 * j;
        unsafeAtomicAdd(a, v0);
        unsafeAtomicAdd(a + 1, v1);
    }
}

// ---- between layers: p = dinv ⊙ relu(dinv·s1 + b1); G=bf16(p), S=p (in place) ----
__global__ void pk(float* __restrict__ S, bf16* __restrict__ G,
                   const float* __restrict__ dinv, const void* __restrict__ b1,
                   const int* __restrict__ flags, int n) {
    const bool isbf = flags[0] != 0;
    int i = blockIdx.x * blockDim.x + threadIdx.x;
    if (i < n * 64) {
        int r = i >> 6, j = i & 63;
        float dv = dinv[r];
        float h = dv * S[i] + ldf(b1, j, isbf);
        h = h > 0.f ? h : 0.f;
        float pv = dv * h;
        G[i] = __float2bfloat16(pv);
        S[i] = pv;  // self-loop init for layer-2 aggregation
    }
}

// ---- final: out = (dinv ⊙ s2) @ W2 + b2, store in detected dtype ----
__global__ __launch_bounds__(256) void outgemm(const float* __restrict__ S,
                                               const void* __restrict__ W2,
                                               const float* __restrict__ dinv,
                                               const void* __restrict__ b2,
                                               const int* __restrict__ flags,
                                               void* __restrict__ outp, int n) {
    const bool isbf = flags[0] != 0;
    __shared__ float ws[64 * 128];  // 32 KB
    for (int i = threadIdx.x; i < 64 * 128; i += 256) ws[i] = ldf(W2, i, isbf);
    __syncthreads();

    const int lane = threadIdx.x & 63;
    const int wid  = (blockIdx.x * 256 + threadIdx.x) >> 6;
    const int nw   = (gridDim.x * 256) >> 6;
    const float blo = ldf(b2, lane, isbf);
    const float bhi = ldf(b2, 64 + lane, isbf);

    for (int row = wid; row < n; row += nw) {
        float xv = dinv[row] * S[(size_t)row * 64 + lane];
        float h0 = 0.f, h1 = 0.f;
#pragma unroll
        for (int m = 0; m < 64; ++m) {
            float s = __shfl(xv, m);
            h0 = fmaf(s, ws[m * 128 + lane], h0);
            h1 = fmaf(s, ws[m * 128 + 64 + lane], h1);
        }
        size_t base = (size_t)row * 128;
        float o0 = h0 + blo, o1 = h1 + bhi;
        if (isbf) {
            ((bf16*)outp)[base + lane]      = __float2bfloat16(o0);
            ((bf16*)outp)[base + 64 + lane] = __float2bfloat16(o1);
        } else {
            ((float*)outp)[base + lane]      = o0;
            ((float*)outp)[base + 64 + lane] = o1;
        }
    }
}

extern "C" void kernel_launch(void* const* d_in, const int* in_sizes, int n_in,
                              void* d_out, int out_size, void* d_ws, size_t ws_size,
                              hipStream_t stream) {
    const void* x  = d_in[0];
    const void* ei = d_in[1];
    const void* ew = d_in[2];
    const void* W1 = d_in[3];
    const void* b1 = d_in[4];
    const void* W2 = d_in[5];
    const void* b2 = d_in[6];

    const int n = in_sizes[0] / 128;   // 100000
    const int e = in_sizes[2];         // 1600000

    // ws layout: flags(8 ints) | dinv(n) | S(64n) | [G(64n bf16) if it fits]
    float* wsf   = (float*)d_ws;
    int*   flags = (int*)d_ws;
    float* dinv  = wsf + 8;
    float* S     = dinv + n;
    size_t need_full = (size_t)(8 + 65 * (size_t)n) * 4 + (size_t)n * 64 * 2;
    bf16* G = (ws_size >= need_full) ? (bf16*)(S + (size_t)n * 64)
                                     : (bf16*)d_out;  // d_out as scratch; only read before outgemm writes

    detect<<<1, 256, 0, stream>>>((const unsigned*)W1, (const unsigned*)ei, flags);

    init_deg<<<(n + 255) / 256, 256, 0, stream>>>(dinv, n);
    deg_accum<<<(e + 255) / 256, 256, 0, stream>>>(ei, ew, dinv, flags, e, n);
    deg_to_dinv<<<(n + 255) / 256, 256, 0, stream>>>(dinv, n);

    gemm1<<<1024, 256, 0, stream>>>(x, W1, dinv, flags, G, S, n);
    scatter64<<<4096, 256, 0, stream>>>(ei, ew, G, S, flags, e, n);
    pk<<<(n * 64 + 255) / 256, 256, 0, stream>>>(S, G, dinv, b1, flags, n);
    scatter64<<<4096, 256, 0, stream>>>(ei, ew, G, S, flags, e, n);
    outgemm<<<1024, 256, 0, stream>>>(S, W2, dinv, b2, flags, d_out, n);
}

// Round 4
// 1301.767 us; speedup vs baseline: 1.5902x; 1.5902x over previous
//
#include <hip/hip_runtime.h>
#include <hip/hip_bf16.h>

typedef __hip_bfloat16 bf16;

__device__ __forceinline__ float bf2f(bf16 v) { return __bfloat162float(v); }

// dtype-dispatching loads (flag-driven, uniform branch)
__device__ __forceinline__ float ldf(const void* p, size_t i, bool isbf) {
    return isbf ? bf2f(((const bf16*)p)[i]) : ((const float*)p)[i];
}
__device__ __forceinline__ int ldi(const void* p, size_t i, bool is64) {
    return is64 ? (int)((const long long*)p)[i] : ((const int*)p)[i];
}
__device__ __forceinline__ float sane(float v) {  // sanitize edge weights
    return (v == v && fabsf(v) < 1e30f) ? v : 0.f;
}

// ---------------- dtype detection ----------------
// flags[0]: 1 if floats are bf16, 0 if fp32.  flags[1]: 1 if indices are int64.
__global__ void detect(const unsigned* __restrict__ w1w, const unsigned* __restrict__ eiw,
                       int* __restrict__ flags) {
    __shared__ int cnt[2];
    if (threadIdx.x < 2) cnt[threadIdx.x] = 0;
    __syncthreads();
    int c0 = 0;
    for (int i = threadIdx.x; i < 4096; i += 256) {
        unsigned u = w1w[i];
        unsigned e0 = (u >> 7) & 0xFFu, e1 = (u >> 23) & 0xFFu;
        if (e0 <= 125u && e1 <= 125u) c0++;   // both halves plausible small bf16
    }
    int c1 = 0;
    for (int i = threadIdx.x; i < 2048; i += 256)
        if (eiw[2 * i + 1] == 0u) c1++;       // int64 high words are all zero
    atomicAdd(&cnt[0], c0);
    atomicAdd(&cnt[1], c1);
    __syncthreads();
    if (threadIdx.x == 0) {
        flags[0] = (cnt[0] >= 3072) ? 1 : 0;
        flags[1] = (cnt[1] >= 1024) ? 1 : 0;
    }
}

// ---------------- init: deg=1 (self-loop), cnt=0 ----------------
__global__ void initk(float* __restrict__ deg, int* __restrict__ cnt, int n) {
    int i = blockIdx.x * blockDim.x + threadIdx.x;
    if (i < n) { deg[i] = 1.0f; cnt[i] = 0; }
}

// ---------------- count in-degree + weighted degree ----------------
__global__ void degcnt(const void* __restrict__ ei, const void* __restrict__ w,
                       float* __restrict__ deg, int* __restrict__ cnt,
                       const int* __restrict__ flags, int e, int n) {
    const bool isbf = flags[0] != 0;
    const bool is64 = flags[1] != 0;
    int i = blockIdx.x * blockDim.x + threadIdx.x;
    if (i < e) {
        int c = ldi(ei, (size_t)e + i, is64);  // col
        if ((unsigned)c < (unsigned)n) {
            atomicAdd(&cnt[c], 1);
            unsafeAtomicAdd(&deg[c], sane(ldf(w, i, isbf)));
        }
    }
}

// ---------------- scan pass 1: per-1024-block exclusive scan ----------------
__global__ __launch_bounds__(1024) void scan1(const int* __restrict__ cnt,
                                              int* __restrict__ rp,
                                              int* __restrict__ bsum, int n) {
    __shared__ int s[1024];
    int gid = blockIdx.x * 1024 + threadIdx.x;
    int v = (gid < n) ? cnt[gid] : 0;
    s[threadIdx.x] = v;
    __syncthreads();
    for (int off = 1; off < 1024; off <<= 1) {
        int t = 0;
        if (threadIdx.x >= off) t = s[threadIdx.x - off];
        __syncthreads();
        if (threadIdx.x >= off) s[threadIdx.x] += t;
        __syncthreads();
    }
    if (gid < n) rp[gid] = s[threadIdx.x] - v;  // exclusive
    if (threadIdx.x == 1023) bsum[blockIdx.x] = s[1023];
}

// ---------------- scan pass 2: scan of block sums (nb <= 1024) ----------------
__global__ __launch_bounds__(1024) void scan2(const int* __restrict__ bsum,
                                              int* __restrict__ bsx, int nb) {
    __shared__ int s[1024];
    int v = (threadIdx.x < nb) ? bsum[threadIdx.x] : 0;
    s[threadIdx.x] = v;
    __syncthreads();
    for (int off = 1; off < 1024; off <<= 1) {
        int t = 0;
        if (threadIdx.x >= off) t = s[threadIdx.x - off];
        __syncthreads();
        if (threadIdx.x >= off) s[threadIdx.x] += t;
        __syncthreads();
    }
    if (threadIdx.x < nb) bsx[threadIdx.x] = s[threadIdx.x] - v;  // exclusive
}

// ---------------- scan pass 3: add block offsets; cursor=rp; dinv ----------------
__global__ void scan3(int* __restrict__ rp, int* __restrict__ cursor,
                      const int* __restrict__ bsx, float* __restrict__ deg,
                      int n, int e) {
    int i = blockIdx.x * blockDim.x + threadIdx.x;
    if (i < n) {
        int v = rp[i] + bsx[i >> 10];
        rp[i] = v;
        cursor[i] = v;
        float d = deg[i];
        deg[i] = d > 0.f ? rsqrtf(d) : 0.f;  // deg becomes dinv in place
    }
    if (i == 0) rp[n] = e;
}

// ---------------- fill CSR: epack[pos] = {row, w_f32bits} ----------------
__global__ void fill(const void* __restrict__ ei, const void* __restrict__ w,
                     int* __restrict__ cursor, uint2* __restrict__ epack,
                     const int* __restrict__ flags, int e, int n) {
    const bool isbf = flags[0] != 0;
    const bool is64 = flags[1] != 0;
    int i = blockIdx.x * blockDim.x + threadIdx.x;
    if (i < e) {
        int r = ldi(ei, (size_t)i, is64);
        int c = ldi(ei, (size_t)e + i, is64);
        if ((unsigned)r < (unsigned)n && (unsigned)c < (unsigned)n) {
            float wv = sane(ldf(w, i, isbf));
            int pos = atomicAdd(&cursor[c], 1);
            epack[pos] = make_uint2((unsigned)r, __float_as_uint(wv));
        }
    }
}

// ---- layer1 GEMM: G1 = bf16(dinv ⊙ (X @ W1)) ----
__global__ __launch_bounds__(256) void gemm1(const void* __restrict__ x,
                                             const void* __restrict__ W1,
                                             const float* __restrict__ dinv,
                                             const int* __restrict__ flags,
                                             bf16* __restrict__ G1, int n) {
    const bool isbf = flags[0] != 0;
    __shared__ float ws[128 * 64];  // 32 KB
    for (int i = threadIdx.x; i < 128 * 64; i += 256) ws[i] = ldf(W1, i, isbf);
    __syncthreads();

    const int lane = threadIdx.x & 63;
    const int wid  = (blockIdx.x * 256 + threadIdx.x) >> 6;
    const int nw   = (gridDim.x * 256) >> 6;

    for (int row = wid; row < n; row += nw) {
        const size_t base = (size_t)row * 128;
        const float xa = ldf(x, base + 2 * lane, isbf);
        const float xb = ldf(x, base + 2 * lane + 1, isbf);
        float h = 0.f;
#pragma unroll
        for (int m = 0; m < 64; ++m) {
            h = fmaf(__shfl(xa, m), ws[(2 * m) * 64 + lane], h);
            h = fmaf(__shfl(xb, m), ws[(2 * m + 1) * 64 + lane], h);
        }
        G1[(size_t)row * 64 + lane] = __float2bfloat16(dinv[row] * h);
    }
}

// ---- agg1: one wave per node. acc = G1[c] + Σ w·G1[r]; fuse relu/bias/dinv → G2 ----
__global__ __launch_bounds__(256) void agg1(const int* __restrict__ rp,
                                            const uint2* __restrict__ epack,
                                            const bf16* __restrict__ G1,
                                            const float* __restrict__ dinv,
                                            const void* __restrict__ b1,
                                            const int* __restrict__ flags,
                                            bf16* __restrict__ G2, int n) {
    const bool isbf = flags[0] != 0;
    const int lane = threadIdx.x & 63;
    const int node = (blockIdx.x * 256 + threadIdx.x) >> 6;
    if (node >= n) return;

    const int s0 = rp[node], s1 = rp[node + 1];
    float acc = bf2f(G1[(size_t)node * 64 + lane]);  // self-loop term

    for (int base = s0; base < s1; base += 64) {
        const int m = min(64, s1 - base);
        uint2 ld = make_uint2(0u, 0u);
        if (lane < m) ld = epack[base + lane];
        for (int k = 0; k < m; ++k) {
            int   r = __shfl((int)ld.x, k);
            float w = __uint_as_float((unsigned)__shfl((int)ld.y, k));
            acc = fmaf(w, bf2f(G1[(size_t)r * 64 + lane]), acc);
        }
    }
    const float dv = dinv[node];
    float h = dv * acc + ldf(b1, lane, isbf);
    h = h > 0.f ? h : 0.f;
    G2[(size_t)node * 64 + lane] = __float2bfloat16(dv * h);
}

// ---- agg2: one wave per node. t = dinv·(G2[c] + Σ w·G2[r]); out = t@W2 + b2 ----
__global__ __launch_bounds__(256) void agg2(const int* __restrict__ rp,
                                            const uint2* __restrict__ epack,
                                            const bf16* __restrict__ G2,
                                            const float* __restrict__ dinv,
                                            const void* __restrict__ W2,
                                            const void* __restrict__ b2,
                                            const int* __restrict__ flags,
                                            void* __restrict__ outp, int n) {
    const bool isbf = flags[0] != 0;
    __shared__ float ws[64 * 128];  // 32 KB
    for (int i = threadIdx.x; i < 64 * 128; i += 256) ws[i] = ldf(W2, i, isbf);
    __syncthreads();

    const int lane = threadIdx.x & 63;
    const int node = (blockIdx.x * 256 + threadIdx.x) >> 6;
    if (node >= n) return;

    const int s0 = rp[node], s1 = rp[node + 1];
    float acc = bf2f(G2[(size_t)node * 64 + lane]);  // self-loop term

    for (int base = s0; base < s1; base += 64) {
        const int m = min(64, s1 - base);
        uint2 ld = make_uint2(0u, 0u);
        if (lane < m) ld = epack[base + lane];
        for (int k = 0; k < m; ++k) {
            int   r = __shfl((int)ld.x, k);
            float w = __uint_as_float((unsigned)__shfl((int)ld.y, k));
            acc = fmaf(w, bf2f(G2[(size_t)r * 64 + lane]), acc);
        }
    }

    const float t = dinv[node] * acc;
    float h0 = 0.f, h1 = 0.f;
#pragma unroll
    for (int m = 0; m < 64; ++m) {
        float s = __shfl(t, m);
        h0 = fmaf(s, ws[m * 128 + lane], h0);
        h1 = fmaf(s, ws[m * 128 + 64 + lane], h1);
    }
    const size_t base = (size_t)node * 128;
    float o0 = h0 + ldf(b2, lane, isbf);
    float o1 = h1 + ldf(b2, 64 + lane, isbf);
    if (isbf) {
        ((bf16*)outp)[base + lane]      = __float2bfloat16(o0);
        ((bf16*)outp)[base + 64 + lane] = __float2bfloat16(o1);
    } else {
        ((float*)outp)[base + lane]      = o0;
        ((float*)outp)[base + 64 + lane] = o1;
    }
}

extern "C" void kernel_launch(void* const* d_in, const int* in_sizes, int n_in,
                              void* d_out, int out_size, void* d_ws, size_t ws_size,
                              hipStream_t stream) {
    const void* x  = d_in[0];
    const void* ei = d_in[1];
    const void* ew = d_in[2];
    const void* W1 = d_in[3];
    const void* b1 = d_in[4];
    const void* W2 = d_in[5];
    const void* b2 = d_in[6];

    const int n = in_sizes[0] / 128;   // 100000
    const int e = in_sizes[2];         // 1600000
    const int nb = (n + 1023) / 1024;  // scan blocks

    // ws layout (4B words):
    // flags(8) | deg/dinv(n) | cnt(n) | rp(n+1) | cursor(n) | bsum(1024) | bsx(1024)
    // | pad | epack(2e words, 8B-aligned) | G1(n*64 bf16) | G2(n*64 bf16)
    int*   flags  = (int*)d_ws;
    float* deg    = (float*)d_ws + 8;            // becomes dinv in scan3
    int*   cnt    = (int*)(deg + n);
    int*   rp     = cnt + n;
    int*   cursor = rp + n + 1;
    int*   bsum   = cursor + n;
    int*   bsx    = bsum + 1024;
    size_t w_off  = (size_t)(8 + 4 * (size_t)n + 1 + 2048);
    w_off = (w_off + 1) & ~(size_t)1;            // 8B align for uint2
    uint2* epack  = (uint2*)((int*)d_ws + w_off);
    bf16*  G1     = (bf16*)(epack + e);
    bf16*  G2     = G1 + (size_t)n * 64;

    detect<<<1, 256, 0, stream>>>((const unsigned*)W1, (const unsigned*)ei, flags);
    initk<<<(n + 255) / 256, 256, 0, stream>>>(deg, cnt, n);
    degcnt<<<(e + 255) / 256, 256, 0, stream>>>(ei, ew, deg, cnt, flags, e, n);
    scan1<<<nb, 1024, 0, stream>>>(cnt, rp, bsum, n);
    scan2<<<1, 1024, 0, stream>>>(bsum, bsx, nb);
    scan3<<<(n + 255) / 256, 256, 0, stream>>>(rp, cursor, bsx, deg, n, e);
    fill<<<(e + 255) / 256, 256, 0, stream>>>(ei, ew, cursor, epack, flags, e, n);

    gemm1<<<1024, 256, 0, stream>>>(x, W1, deg, flags, G1, n);
    agg1<<<(n * 64 + 255) / 256, 256, 0, stream>>>(rp, epack, G1, deg, b1, flags, G2, n);
    agg2<<<(n * 64 + 255) / 256, 256, 0, stream>>>(rp, epack, G2, deg, W2, b2, flags, d_out, n);
}

// Round 5
// 1061.885 us; speedup vs baseline: 1.9494x; 1.2259x over previous
//
#include <hip/hip_runtime.h>
#include <hip/hip_bf16.h>

typedef __hip_bfloat16 bf16;

__device__ __forceinline__ float bf2f(bf16 v) { return __bfloat162float(v); }
__device__ __forceinline__ float lo16(unsigned u) { return __uint_as_float((u & 0xffffu) << 16); }
__device__ __forceinline__ float hi16(unsigned u) { return __uint_as_float(u & 0xffff0000u); }
__device__ __forceinline__ unsigned short f2bfbits(float f) {
    return (unsigned short)(__hip_bfloat16_raw(__float2bfloat16(f)).x);
}
__device__ __forceinline__ unsigned pack2(float a, float b) {
    return (unsigned)f2bfbits(a) | ((unsigned)f2bfbits(b) << 16);
}

// dtype-dispatching loads (flag-driven, uniform branch)
__device__ __forceinline__ float ldf(const void* p, size_t i, bool isbf) {
    return isbf ? bf2f(((const bf16*)p)[i]) : ((const float*)p)[i];
}
__device__ __forceinline__ int ldi(const void* p, size_t i, bool is64) {
    return is64 ? (int)((const long long*)p)[i] : ((const int*)p)[i];
}
__device__ __forceinline__ float sane(float v) {
    return (v == v && fabsf(v) < 1e30f) ? v : 0.f;
}

// ---------------- dtype detection ----------------
__global__ void detect(const unsigned* __restrict__ w1w, const unsigned* __restrict__ eiw,
                       int* __restrict__ flags) {
    __shared__ int cnt[2];
    if (threadIdx.x < 2) cnt[threadIdx.x] = 0;
    __syncthreads();
    int c0 = 0;
    for (int i = threadIdx.x; i < 4096; i += 256) {
        unsigned u = w1w[i];
        unsigned e0 = (u >> 7) & 0xFFu, e1 = (u >> 23) & 0xFFu;
        if (e0 <= 125u && e1 <= 125u) c0++;
    }
    int c1 = 0;
    for (int i = threadIdx.x; i < 2048; i += 256)
        if (eiw[2 * i + 1] == 0u) c1++;
    atomicAdd(&cnt[0], c0);
    atomicAdd(&cnt[1], c1);
    __syncthreads();
    if (threadIdx.x == 0) {
        flags[0] = (cnt[0] >= 3072) ? 1 : 0;
        flags[1] = (cnt[1] >= 1024) ? 1 : 0;
    }
}

// ---------------- init ----------------
__global__ void initk(float* __restrict__ deg, int* __restrict__ cnt, int n) {
    int i = blockIdx.x * blockDim.x + threadIdx.x;
    if (i < n) { deg[i] = 1.0f; cnt[i] = 0; }
}

// ---------------- count in-degree + weighted degree ----------------
__global__ void degcnt(const void* __restrict__ ei, const void* __restrict__ w,
                       float* __restrict__ deg, int* __restrict__ cnt,
                       const int* __restrict__ flags, int e, int n) {
    const bool isbf = flags[0] != 0;
    const bool is64 = flags[1] != 0;
    int i = blockIdx.x * blockDim.x + threadIdx.x;
    if (i < e) {
        int c = ldi(ei, (size_t)e + i, is64);
        if ((unsigned)c < (unsigned)n) {
            atomicAdd(&cnt[c], 1);
            unsafeAtomicAdd(&deg[c], sane(ldf(w, i, isbf)));
        }
    }
}

// ---------------- scans ----------------
__global__ __launch_bounds__(1024) void scan1(const int* __restrict__ cnt,
                                              int* __restrict__ rp,
                                              int* __restrict__ bsum, int n) {
    __shared__ int s[1024];
    int gid = blockIdx.x * 1024 + threadIdx.x;
    int v = (gid < n) ? cnt[gid] : 0;
    s[threadIdx.x] = v;
    __syncthreads();
    for (int off = 1; off < 1024; off <<= 1) {
        int t = 0;
        if (threadIdx.x >= off) t = s[threadIdx.x - off];
        __syncthreads();
        if (threadIdx.x >= off) s[threadIdx.x] += t;
        __syncthreads();
    }
    if (gid < n) rp[gid] = s[threadIdx.x] - v;
    if (threadIdx.x == 1023) bsum[blockIdx.x] = s[1023];
}

__global__ __launch_bounds__(1024) void scan2(const int* __restrict__ bsum,
                                              int* __restrict__ bsx, int nb) {
    __shared__ int s[1024];
    int v = (threadIdx.x < nb) ? bsum[threadIdx.x] : 0;
    s[threadIdx.x] = v;
    __syncthreads();
    for (int off = 1; off < 1024; off <<= 1) {
        int t = 0;
        if (threadIdx.x >= off) t = s[threadIdx.x - off];
        __syncthreads();
        if (threadIdx.x >= off) s[threadIdx.x] += t;
        __syncthreads();
    }
    if (threadIdx.x < nb) bsx[threadIdx.x] = s[threadIdx.x] - v;
}

__global__ void scan3(int* __restrict__ rp, int* __restrict__ cursor,
                      const int* __restrict__ bsx, float* __restrict__ deg,
                      int n, int e) {
    int i = blockIdx.x * blockDim.x + threadIdx.x;
    if (i < n) {
        int v = rp[i] + bsx[i >> 10];
        rp[i] = v;
        cursor[i] = v;
        float d = deg[i];
        deg[i] = d > 0.f ? rsqrtf(d) : 0.f;
    }
    if (i == 0) rp[n] = e;
}

// ---------------- fill CSR ----------------
__global__ void fill(const void* __restrict__ ei, const void* __restrict__ w,
                     int* __restrict__ cursor, uint2* __restrict__ epack,
                     const int* __restrict__ flags, int e, int n) {
    const bool isbf = flags[0] != 0;
    const bool is64 = flags[1] != 0;
    int i = blockIdx.x * blockDim.x + threadIdx.x;
    if (i < e) {
        int r = ldi(ei, (size_t)i, is64);
        int c = ldi(ei, (size_t)e + i, is64);
        if ((unsigned)r < (unsigned)n && (unsigned)c < (unsigned)n) {
            float wv = sane(ldf(w, i, isbf));
            int pos = atomicAdd(&cursor[c], 1);
            epack[pos] = make_uint2((unsigned)r, __float_as_uint(wv));
        }
    }
}

// ---- layer1 GEMM: G1 = bf16(dinv ⊙ (X @ W1)), rows packed as 32 uints ----
__global__ __launch_bounds__(256) void gemm1(const void* __restrict__ x,
                                             const void* __restrict__ W1,
                                             const float* __restrict__ dinv,
                                             const int* __restrict__ flags,
                                             unsigned* __restrict__ G1, int n) {
    const bool isbf = flags[0] != 0;
    __shared__ float ws[128 * 64];
    for (int i = threadIdx.x; i < 128 * 64; i += 256) ws[i] = ldf(W1, i, isbf);
    __syncthreads();

    const int lane = threadIdx.x & 63;
    const int wid  = (blockIdx.x * 256 + threadIdx.x) >> 6;
    const int nw   = (gridDim.x * 256) >> 6;

    for (int row = wid; row < n; row += nw) {
        const size_t base = (size_t)row * 128;
        const float xa = ldf(x, base + 2 * lane, isbf);
        const float xb = ldf(x, base + 2 * lane + 1, isbf);
        float h = 0.f;
#pragma unroll
        for (int m = 0; m < 64; ++m) {
            h = fmaf(__shfl(xa, m), ws[(2 * m) * 64 + lane], h);
            h = fmaf(__shfl(xb, m), ws[(2 * m + 1) * 64 + lane], h);
        }
        float gv = dinv[row] * h;
        // lane holds dim `lane`; lanes 2j,2j+1 pack into uint j via shfl_xor
        float other = __shfl_xor(gv, 1);
        if ((lane & 1) == 0)
            G1[(size_t)row * 32 + (lane >> 1)] = pack2(gv, other);
    }
}

// ---- gather-accumulate core: half-wave per node, 8-deep prefetch ----
// acc0/acc1 = dims (2j, 2j+1) of: G[node] + sum w * G[r]
__device__ __forceinline__ void gather_acc(const int* __restrict__ rp,
                                           const uint2* __restrict__ epack,
                                           const unsigned* __restrict__ G,
                                           int node, int j,
                                           float& acc0, float& acc1) {
    const int s0 = rp[node], s1 = rp[node + 1];
    unsigned gself = G[(size_t)node * 32 + j];
    acc0 = lo16(gself);
    acc1 = hi16(gself);

    for (int base = s0; base < s1; base += 32) {
        const int m = min(32, s1 - base);
        uint2 ld = make_uint2(0u, 0u);
        if (j < m) ld = epack[base + j];
        int k = 0;
        for (; k + 8 <= m; k += 8) {
            int r[8]; float w[8]; unsigned gp[8];
#pragma unroll
            for (int u = 0; u < 8; ++u) {
                r[u] = __shfl((int)ld.x, k + u, 32);
                w[u] = __uint_as_float((unsigned)__shfl((int)ld.y, k + u, 32));
            }
#pragma unroll
            for (int u = 0; u < 8; ++u) gp[u] = G[(size_t)r[u] * 32 + j];
#pragma unroll
            for (int u = 0; u < 8; ++u) {
                acc0 = fmaf(w[u], lo16(gp[u]), acc0);
                acc1 = fmaf(w[u], hi16(gp[u]), acc1);
            }
        }
        for (; k < m; ++k) {
            int   r = __shfl((int)ld.x, k, 32);
            float w = __uint_as_float((unsigned)__shfl((int)ld.y, k, 32));
            unsigned gp = G[(size_t)r * 32 + j];
            acc0 = fmaf(w, lo16(gp), acc0);
            acc1 = fmaf(w, hi16(gp), acc1);
        }
    }
}

// ---- agg1: fuse relu/bias/dinv -> G2 (packed) ----
__global__ __launch_bounds__(256) void agg1(const int* __restrict__ rp,
                                            const uint2* __restrict__ epack,
                                            const unsigned* __restrict__ G1,
                                            const float* __restrict__ dinv,
                                            const void* __restrict__ b1,
                                            const int* __restrict__ flags,
                                            unsigned* __restrict__ G2, int n) {
    const bool isbf = flags[0] != 0;
    const int j    = threadIdx.x & 31;
    const int node = (blockIdx.x * 256 + threadIdx.x) >> 5;
    if (node >= n) return;

    float acc0, acc1;
    gather_acc(rp, epack, G1, node, j, acc0, acc1);

    const float dv = dinv[node];
    float h0 = dv * acc0 + ldf(b1, 2 * j, isbf);
    float h1 = dv * acc1 + ldf(b1, 2 * j + 1, isbf);
    h0 = h0 > 0.f ? h0 : 0.f;
    h1 = h1 > 0.f ? h1 : 0.f;
    G2[(size_t)node * 32 + j] = pack2(dv * h0, dv * h1);
}

// ---- agg2: t = dinv*(G2[c] + sum w*G2[r]); out = t @ W2 + b2 ----
__global__ __launch_bounds__(256) void agg2(const int* __restrict__ rp,
                                            const uint2* __restrict__ epack,
                                            const unsigned* __restrict__ G2,
                                            const float* __restrict__ dinv,
                                            const void* __restrict__ W2,
                                            const void* __restrict__ b2,
                                            const int* __restrict__ flags,
                                            void* __restrict__ outp, int n) {
    const bool isbf = flags[0] != 0;
    __shared__ float ws[64 * 128];
    for (int i = threadIdx.x; i < 64 * 128; i += 256) ws[i] = ldf(W2, i, isbf);
    __syncthreads();

    const int j    = threadIdx.x & 31;
    const int node = (blockIdx.x * 256 + threadIdx.x) >> 5;
    if (node >= n) return;

    float acc0, acc1;
    gather_acc(rp, epack, G2, node, j, acc0, acc1);

    const float dv = dinv[node];
    const float t0 = dv * acc0;  // dim 2j
    const float t1 = dv * acc1;  // dim 2j+1

    float h[4] = {0.f, 0.f, 0.f, 0.f};  // outputs j, j+32, j+64, j+96
#pragma unroll
    for (int mm = 0; mm < 32; ++mm) {
        float s0 = __shfl(t0, mm, 32);  // t[2*mm]
        float s1 = __shfl(t1, mm, 32);  // t[2*mm+1]
        const float* w0 = ws + (2 * mm) * 128;
        const float* w1 = ws + (2 * mm + 1) * 128;
#pragma unroll
        for (int q = 0; q < 4; ++q) {
            h[q] = fmaf(s0, w0[j + 32 * q], h[q]);
            h[q] = fmaf(s1, w1[j + 32 * q], h[q]);
        }
    }

    const size_t base = (size_t)node * 128;
#pragma unroll
    for (int q = 0; q < 4; ++q) {
        float o = h[q] + ldf(b2, j + 32 * q, isbf);
        if (isbf) ((bf16*)outp)[base + j + 32 * q] = __float2bfloat16(o);
        else      ((float*)outp)[base + j + 32 * q] = o;
    }
}

extern "C" void kernel_launch(void* const* d_in, const int* in_sizes, int n_in,
                              void* d_out, int out_size, void* d_ws, size_t ws_size,
                              hipStream_t stream) {
    const void* x  = d_in[0];
    const void* ei = d_in[1];
    const void* ew = d_in[2];
    const void* W1 = d_in[3];
    const void* b1 = d_in[4];
    const void* W2 = d_in[5];
    const void* b2 = d_in[6];

    const int n = in_sizes[0] / 128;   // 100000
    const int e = in_sizes[2];         // 1600000
    const int nb = (n + 1023) / 1024;

    int*   flags  = (int*)d_ws;
    float* deg    = (float*)d_ws + 8;            // becomes dinv in scan3
    int*   cnt    = (int*)(deg + n);
    int*   rp     = cnt + n;
    int*   cursor = rp + n + 1;
    int*   bsum   = cursor + n;
    int*   bsx    = bsum + 1024;
    size_t w_off  = (size_t)(8 + 4 * (size_t)n + 1 + 2048);
    w_off = (w_off + 1) & ~(size_t)1;            // 8B align
    uint2*    epack = (uint2*)((int*)d_ws + w_off);
    unsigned* G1    = (unsigned*)(epack + e);    // n*32 uints (bf16x2)
    unsigned* G2    = G1 + (size_t)n * 32;

    detect<<<1, 256, 0, stream>>>((const unsigned*)W1, (const unsigned*)ei, flags);
    initk<<<(n + 255) / 256, 256, 0, stream>>>(deg, cnt, n);
    degcnt<<<(e + 255) / 256, 256, 0, stream>>>(ei, ew, deg, cnt, flags, e, n);
    scan1<<<nb, 1024, 0, stream>>>(cnt, rp, bsum, n);
    scan2<<<1, 1024, 0, stream>>>(bsum, bsx, nb);
    scan3<<<(n + 255) / 256, 256, 0, stream>>>(rp, cursor, bsx, deg, n, e);
    fill<<<(e + 255) / 256, 256, 0, stream>>>(ei, ew, cursor, epack, flags, e, n);

    gemm1<<<1024, 256, 0, stream>>>(x, W1, deg, flags, G1, n);
    agg1<<<(n * 32 + 255) / 256, 256, 0, stream>>>(rp, epack, G1, deg, b1, flags, G2, n);
    agg2<<<(n * 32 + 255) / 256, 256, 0, stream>>>(rp, epack, G2, deg, W2, b2, flags, d_out, n);
}